// Round 1
// baseline (1106.047 us; speedup 1.0000x reference)
//
#include <hip/hip_runtime.h>
#include <math.h>

constexpr int B    = 4;
constexpr int L    = 1024;
constexpr int CIN  = 256;
constexpr int H    = 8;
constexpr int DE   = 64;
constexpr int DOUT = 512;

// ---------------------------------------------------------------------------
// Conv1d projections (k=3, pad=1):  out[b][h][l][d] over co = h*64+d
// grid (L/64, B*H, 3), block 256.  LDS: x tile [66][32], W tile [96][65]
// ---------------------------------------------------------------------------
__global__ __launch_bounds__(256) void conv_kernel(
    const float* __restrict__ qx, const float* __restrict__ kx, const float* __restrict__ vx,
    const float* __restrict__ Wq, const float* __restrict__ Wk, const float* __restrict__ Wv,
    const float* __restrict__ bq, const float* __restrict__ bk, const float* __restrict__ bv,
    float* __restrict__ Qh, float* __restrict__ Kh, float* __restrict__ Vh)
{
    const int tz = blockIdx.z;
    const float* __restrict__ x  = (tz == 0) ? qx : (tz == 1) ? kx : vx;
    const float* __restrict__ W  = (tz == 0) ? Wq : (tz == 1) ? Wk : Wv;
    const float* __restrict__ bp = (tz == 0) ? bq : (tz == 1) ? bk : bv;
    float* __restrict__ outp     = (tz == 0) ? Qh : (tz == 1) ? Kh : Vh;

    const int bh = blockIdx.y;          // b*H + h
    const int h  = bh & (H - 1);
    const int b  = bh >> 3;
    const int l0 = blockIdx.x * 64;
    const int tid = threadIdx.x;
    const int d   = tid & 63;           // output channel within head
    const int lg  = tid >> 6;           // 0..3, group of 16 l-positions

    __shared__ float xs[66 * 32];       // [l(-1..64)][ci chunk 32]
    __shared__ float wsm[96 * 65];      // [r = ci*3+t][d], pad 65

    float acc[16];
#pragma unroll
    for (int i = 0; i < 16; ++i) acc[i] = 0.0f;

    for (int c0 = 0; c0 < CIN; c0 += 32) {
        __syncthreads();
        for (int f = tid; f < 66 * 32; f += 256) {
            const int lr = f >> 5, cc = f & 31;
            const int lgl = l0 - 1 + lr;
            float val = 0.0f;
            if (lgl >= 0 && lgl < L)
                val = x[((size_t)b * L + lgl) * CIN + c0 + cc];
            xs[f] = val;
        }
        for (int f = tid; f < 64 * 96; f += 256) {
            const int dd = f / 96, rr = f - dd * 96;
            // W[co][ci][t] flat: co*768 + (c0+ci)*3+t = co*768 + c0*3 + rr
            wsm[rr * 65 + dd] = W[(size_t)(h * 64 + dd) * (CIN * 3) + c0 * 3 + rr];
        }
        __syncthreads();
#pragma unroll 1
        for (int cg = 0; cg < 8; ++cg) {
            float4 xv[18];
#pragma unroll
            for (int r = 0; r < 18; ++r)
                xv[r] = *(const float4*)&xs[(lg * 16 + r) * 32 + cg * 4];
#pragma unroll
            for (int cc = 0; cc < 4; ++cc) {
                const int ci = cg * 4 + cc;
                const float w0 = wsm[(ci * 3 + 0) * 65 + d];
                const float w1 = wsm[(ci * 3 + 1) * 65 + d];
                const float w2 = wsm[(ci * 3 + 2) * 65 + d];
#pragma unroll
                for (int ll = 0; ll < 16; ++ll) {
                    acc[ll] = fmaf(w0, ((const float*)&xv[ll    ])[cc], acc[ll]);
                    acc[ll] = fmaf(w1, ((const float*)&xv[ll + 1])[cc], acc[ll]);
                    acc[ll] = fmaf(w2, ((const float*)&xv[ll + 2])[cc], acc[ll]);
                }
            }
        }
    }
    const float bias = bp[h * 64 + d];
#pragma unroll
    for (int ll = 0; ll < 16; ++ll) {
        const int l = l0 + lg * 16 + ll;
        outp[((size_t)bh * L + l) * 64 + d] = acc[ll] + bias;
    }
}

// ---------------------------------------------------------------------------
// Attention: per (b,h, 32-row q tile).  Online softmax (m,l) + O accumulate;
// raw scores S go to the A-region of d_out, sweep-2 normalizes in place.
// grid (L/32, B*H), block 256.
// Thread (qgrp=tid/16, kgrp=tid%16): owns q rows {2qgrp,2qgrp+1},
// k columns {kgrp+16c | c=0..3} within each 64-wide k tile (stride-16 keeps
// LDS reads at worst 2-way conflicted), and d columns {4*kgrp..} for PV/O.
// ---------------------------------------------------------------------------
__global__ __launch_bounds__(256) void attn_kernel(
    const float* __restrict__ Qh, const float* __restrict__ Kh, const float* __restrict__ Vh,
    const float* __restrict__ w_pos, const int* __restrict__ amask,
    const float* __restrict__ vmaskp,
    float* __restrict__ Aout, float* __restrict__ Oh)
{
    const int bh = blockIdx.y;
    const int b = bh >> 3, h = bh & 7;
    const int q0 = blockIdx.x * 32;
    const int tid = threadIdx.x;
    const int qgrp = tid >> 4;   // 0..15
    const int kgrp = tid & 15;   // 0..15

    __shared__ float smem[10944];
    float* const Qs = smem;              // [32][68]
    float* const KV = smem + 2176;       // [64][68]; also w_pos [65][64] in phase A
    float* const Pl = smem + 6528;       // [32][66]  P[q][rel]
    float* const el = smem + 8640;       // [64][36]  e[k][q]

    // ---- phase A: stage Q tile + w_pos, compute P[q][r] = Q[q] . w_pos[r]
    for (int i4 = tid; i4 < 32 * 16; i4 += 256) {
        const int r = i4 >> 4, c4 = i4 & 15;
        *(float4*)&Qs[r * 68 + c4 * 4] =
            *(const float4*)&Qh[((size_t)bh * L + q0 + r) * 64 + c4 * 4];
    }
    for (int i4 = tid; i4 < 65 * 16; i4 += 256) {
        const int r = i4 >> 4, c4 = i4 & 15;
        *(float4*)&KV[r * 64 + c4 * 4] = *(const float4*)&w_pos[(size_t)r * 64 + c4 * 4];
    }
    __syncthreads();
    for (int o = tid; o < 32 * 65; o += 256) {
        const int qq = o / 65, r = o - qq * 65;
        float s = 0.0f;
#pragma unroll
        for (int i = 0; i < 16; ++i) {
            const float4 a = *(const float4*)&Qs[qq * 68 + i * 4];
            const float4 w = *(const float4*)&KV[r * 64 + i * 4];
            s = fmaf(a.x, w.x, s); s = fmaf(a.y, w.y, s);
            s = fmaf(a.z, w.z, s); s = fmaf(a.w, w.w, s);
        }
        Pl[qq * 66 + r] = s;
    }
    __syncthreads();

    const int row0 = qgrp * 2, row1 = row0 + 1;
    const int qA = q0 + row0, qB = q0 + row1;
    const float Plo0 = Pl[row0 * 66], Phi0 = Pl[row0 * 66 + 64];
    const float Plo1 = Pl[row1 * 66], Phi1 = Pl[row1 * 66 + 64];

    float mreg0 = -INFINITY, mreg1 = -INFINITY;
    float lreg0 = 0.0f, lreg1 = 0.0f;
    float O0[4] = {0, 0, 0, 0}, O1[4] = {0, 0, 0, 0};

    float* const Arow0 = Aout + (size_t)(bh * L + qA) * L;
    float* const Arow1 = Aout + (size_t)(bh * L + qB) * L;

    for (int kt = 0; kt < 16; ++kt) {
        const int kbase = kt * 64;
        __syncthreads();                       // protect KV / el from prev iter
        for (int i4 = tid; i4 < 64 * 16; i4 += 256) {
            const int r = i4 >> 4, c4 = i4 & 15;
            *(float4*)&KV[r * 68 + c4 * 4] =
                *(const float4*)&Kh[((size_t)bh * L + kbase + r) * 64 + c4 * 4];
        }
        __syncthreads();

        // ---- S = QK^T/8 + pos, masked
        float s0[4] = {0, 0, 0, 0}, s1[4] = {0, 0, 0, 0};
#pragma unroll
        for (int i = 0; i < 16; ++i) {
            const float4 qa = *(const float4*)&Qs[row0 * 68 + i * 4];
            const float4 qb = *(const float4*)&Qs[row1 * 68 + i * 4];
#pragma unroll
            for (int c = 0; c < 4; ++c) {
                const float4 kv = *(const float4*)&KV[(kgrp + 16 * c) * 68 + i * 4];
                s0[c] = fmaf(qa.x, kv.x, s0[c]); s0[c] = fmaf(qa.y, kv.y, s0[c]);
                s0[c] = fmaf(qa.z, kv.z, s0[c]); s0[c] = fmaf(qa.w, kv.w, s0[c]);
                s1[c] = fmaf(qb.x, kv.x, s1[c]); s1[c] = fmaf(qb.y, kv.y, s1[c]);
                s1[c] = fmaf(qb.z, kv.z, s1[c]); s1[c] = fmaf(qb.w, kv.w, s1[c]);
            }
        }

        float sv0[4], sv1[4];
#pragma unroll
        for (int c = 0; c < 4; ++c) {
            const int kg = kbase + kgrp + 16 * c;
            {
                float v = s0[c] * 0.125f;
                const int off = kg - qA;
                float pos;
                if (off <= -32) pos = Plo0;
                else if (off >= 32) pos = Phi0;
                else pos = Pl[row0 * 66 + off + 32];
                v += pos;
                if (amask[(size_t)qA * L + kg] != 0) v = -INFINITY;
                sv0[c] = v;
                Arow0[kg] = v;                 // raw score -> A region
            }
            {
                float v = s1[c] * 0.125f;
                const int off = kg - qB;
                float pos;
                if (off <= -32) pos = Plo1;
                else if (off >= 32) pos = Phi1;
                else pos = Pl[row1 * 66 + off + 32];
                v += pos;
                if (amask[(size_t)qB * L + kg] != 0) v = -INFINITY;
                sv1[c] = v;
                Arow1[kg] = v;
            }
        }

        // ---- online softmax update (row spread over the 16 kgrp lanes)
        float tmax0 = fmaxf(fmaxf(sv0[0], sv0[1]), fmaxf(sv0[2], sv0[3]));
        float tmax1 = fmaxf(fmaxf(sv1[0], sv1[1]), fmaxf(sv1[2], sv1[3]));
#pragma unroll
        for (int mm = 1; mm < 16; mm <<= 1) {
            tmax0 = fmaxf(tmax0, __shfl_xor(tmax0, mm, 64));
            tmax1 = fmaxf(tmax1, __shfl_xor(tmax1, mm, 64));
        }
        const float mn0 = fmaxf(mreg0, tmax0);
        const float mn1 = fmaxf(mreg1, tmax1);
        float e0[4], e1[4];
        float al0, al1, es0 = 0.0f, es1 = 0.0f;
        if (mn0 == -INFINITY) {
            al0 = 1.0f;
#pragma unroll
            for (int c = 0; c < 4; ++c) e0[c] = 0.0f;
        } else {
            al0 = __expf(mreg0 - mn0);
#pragma unroll
            for (int c = 0; c < 4; ++c) { e0[c] = __expf(sv0[c] - mn0); es0 += e0[c]; }
        }
        if (mn1 == -INFINITY) {
            al1 = 1.0f;
#pragma unroll
            for (int c = 0; c < 4; ++c) e1[c] = 0.0f;
        } else {
            al1 = __expf(mreg1 - mn1);
#pragma unroll
            for (int c = 0; c < 4; ++c) { e1[c] = __expf(sv1[c] - mn1); es1 += e1[c]; }
        }
#pragma unroll
        for (int mm = 1; mm < 16; mm <<= 1) {
            es0 += __shfl_xor(es0, mm, 64);
            es1 += __shfl_xor(es1, mm, 64);
        }
        lreg0 = lreg0 * al0 + es0; mreg0 = mn0;
        lreg1 = lreg1 * al1 + es1; mreg1 = mn1;
#pragma unroll
        for (int c = 0; c < 4; ++c) { O0[c] *= al0; O1[c] *= al1; }
#pragma unroll
        for (int c = 0; c < 4; ++c)
            *(float2*)&el[(kgrp + 16 * c) * 36 + row0] = make_float2(e0[c], e1[c]);

        __syncthreads();                       // el visible; KV reads done
        for (int i4 = tid; i4 < 64 * 16; i4 += 256) {
            const int r = i4 >> 4, c4 = i4 & 15;
            *(float4*)&KV[r * 68 + c4 * 4] =
                *(const float4*)&Vh[((size_t)bh * L + kbase + r) * 64 + c4 * 4];
        }
        __syncthreads();

        // ---- PV: O[q][d] += e[q][k] * V[k][d]   (d = 4*kgrp .. +3)
#pragma unroll 4
        for (int kk = 0; kk < 64; ++kk) {
            const float2 ee = *(const float2*)&el[kk * 36 + row0];
            const float4 vv = *(const float4*)&KV[kk * 68 + kgrp * 4];
            O0[0] = fmaf(ee.x, vv.x, O0[0]); O0[1] = fmaf(ee.x, vv.y, O0[1]);
            O0[2] = fmaf(ee.x, vv.z, O0[2]); O0[3] = fmaf(ee.x, vv.w, O0[3]);
            O1[0] = fmaf(ee.y, vv.x, O1[0]); O1[1] = fmaf(ee.y, vv.y, O1[1]);
            O1[2] = fmaf(ee.y, vv.z, O1[2]); O1[3] = fmaf(ee.y, vv.w, O1[3]);
        }
    }

    const float il0 = (lreg0 > 0.0f) ? 1.0f / lreg0 : 0.0f;
    const float il1 = (lreg1 > 0.0f) ? 1.0f / lreg1 : 0.0f;
    {
        float4 o0 = make_float4(O0[0] * il0, O0[1] * il0, O0[2] * il0, O0[3] * il0);
        float4 o1 = make_float4(O1[0] * il1, O1[1] * il1, O1[2] * il1, O1[3] * il1);
        *(float4*)&Oh[((size_t)b * L + qA) * DOUT + h * 64 + kgrp * 4] = o0;
        *(float4*)&Oh[((size_t)b * L + qB) * DOUT + h * 64 + kgrp * 4] = o1;
    }

    // ---- sweep 2: normalize A in place (same-thread addresses only)
    const float vm = vmaskp[0];
    for (int kt = 0; kt < 16; ++kt) {
#pragma unroll
        for (int c = 0; c < 4; ++c) {
            const int kg = kt * 64 + kgrp + 16 * c;
            {
                const float s = Arow0[kg];
                const float e = (mreg0 == -INFINITY) ? 0.0f : __expf(s - mreg0);
                float a = e * il0;
                if (!(a > vm)) a = 0.0f;
                Arow0[kg] = a;
            }
            {
                const float s = Arow1[kg];
                const float e = (mreg1 == -INFINITY) ? 0.0f : __expf(s - mreg1);
                float a = e * il1;
                if (!(a > vm)) a = 0.0f;
                Arow1[kg] = a;
            }
        }
    }
}

// ---------------------------------------------------------------------------
// FC: out[row][j] = O[row][:] . Wfc[j][:] + bfc[j]   rows = B*L
// grid (B*L/64, DOUT/64), block 256, 4x4 register tile per thread.
// ---------------------------------------------------------------------------
__global__ __launch_bounds__(256) void fc_kernel(
    const float* __restrict__ Ohp, const float* __restrict__ Wfc,
    const float* __restrict__ bfc, float* __restrict__ outp)
{
    __shared__ float Os[64 * 68];
    __shared__ float Ws[64 * 68];
    const int r0 = blockIdx.x * 64;
    const int j0 = blockIdx.y * 64;
    const int tid = threadIdx.x;
    const int rg = tid >> 4, cg = tid & 15;

    float acc[4][4];
#pragma unroll
    for (int r = 0; r < 4; ++r)
#pragma unroll
        for (int c = 0; c < 4; ++c) acc[r][c] = 0.0f;

    for (int kc = 0; kc < DOUT; kc += 64) {
        __syncthreads();
        for (int i4 = tid; i4 < 64 * 16; i4 += 256) {
            const int r = i4 >> 4, c4 = i4 & 15;
            *(float4*)&Os[r * 68 + c4 * 4] =
                *(const float4*)&Ohp[(size_t)(r0 + r) * DOUT + kc + c4 * 4];
            *(float4*)&Ws[r * 68 + c4 * 4] =
                *(const float4*)&Wfc[(size_t)(j0 + r) * DOUT + kc + c4 * 4];
        }
        __syncthreads();
#pragma unroll 4
        for (int i = 0; i < 16; ++i) {
            float4 av[4], wv[4];
#pragma unroll
            for (int r = 0; r < 4; ++r) av[r] = *(const float4*)&Os[(rg * 4 + r) * 68 + i * 4];
#pragma unroll
            for (int c = 0; c < 4; ++c) wv[c] = *(const float4*)&Ws[(cg * 4 + c) * 68 + i * 4];
#pragma unroll
            for (int r = 0; r < 4; ++r)
#pragma unroll
                for (int c = 0; c < 4; ++c) {
                    acc[r][c] = fmaf(av[r].x, wv[c].x, acc[r][c]);
                    acc[r][c] = fmaf(av[r].y, wv[c].y, acc[r][c]);
                    acc[r][c] = fmaf(av[r].z, wv[c].z, acc[r][c]);
                    acc[r][c] = fmaf(av[r].w, wv[c].w, acc[r][c]);
                }
        }
    }
    const float4 bias = *(const float4*)&bfc[j0 + cg * 4];
#pragma unroll
    for (int r = 0; r < 4; ++r) {
        float4 o = make_float4(acc[r][0] + bias.x, acc[r][1] + bias.y,
                               acc[r][2] + bias.z, acc[r][3] + bias.w);
        *(float4*)&outp[(size_t)(r0 + rg * 4 + r) * DOUT + j0 + cg * 4] = o;
    }
}

// ---------------------------------------------------------------------------
extern "C" void kernel_launch(void* const* d_in, const int* in_sizes, int n_in,
                              void* d_out, int out_size, void* d_ws, size_t ws_size,
                              hipStream_t stream) {
    const float* q    = (const float*)d_in[0];
    const float* k    = (const float*)d_in[1];
    const float* v    = (const float*)d_in[2];
    const float* Wq   = (const float*)d_in[3];
    const float* bq   = (const float*)d_in[4];
    const float* Wk   = (const float*)d_in[5];
    const float* bk   = (const float*)d_in[6];
    const float* Wv   = (const float*)d_in[7];
    const float* bv   = (const float*)d_in[8];
    const float* Wfc  = (const float*)d_in[9];
    const float* bfc  = (const float*)d_in[10];
    const float* wpos = (const float*)d_in[11];
    const int*   amsk = (const int*)d_in[12];
    const float* vmsk = (const float*)d_in[13];

    float* ws = (float*)d_ws;
    float* Qh = ws;                                 // [B][H][L][64]
    float* Kh = ws + (size_t)2097152;
    float* Vh = ws + (size_t)2 * 2097152;
    float* Oh = ws + (size_t)3 * 2097152;           // [B][L][512]

    float* outp = (float*)d_out;                    // [B][L][512]
    float* Aout = outp + (size_t)B * L * DOUT;      // [B][H][L][L]

    conv_kernel<<<dim3(L / 64, B * H, 3), 256, 0, stream>>>(
        q, k, v, Wq, Wk, Wv, bq, bk, bv, Qh, Kh, Vh);
    attn_kernel<<<dim3(L / 32, B * H), 256, 0, stream>>>(
        Qh, Kh, Vh, wpos, amsk, vmsk, Aout, Oh);
    fc_kernel<<<dim3(B * L / 64, DOUT / 64), 256, 0, stream>>>(
        Oh, Wfc, bfc, outp);
}

// Round 6
// 657.538 us; speedup vs baseline: 1.6821x; 1.6821x over previous
//
#include <hip/hip_runtime.h>
#include <math.h>

typedef _Float16 f16;
typedef _Float16 f16x8 __attribute__((ext_vector_type(8)));
typedef float f32x4 __attribute__((ext_vector_type(4)));

constexpr int B    = 4;
constexpr int L    = 1024;
constexpr int CIN  = 256;
constexpr int H    = 8;
constexpr int DOUT = 512;

// ---------------------------------------------------------------------------
// Conv1d projections (k=3, pad=1).  Q,K -> f16 [bh][l][64]; V -> f16 [b*512+co][l]
// (pre-transposed so attention's PV B-operand is a contiguous LDS row read).
// grid (L/64, B*H, 3), block 256.
// ---------------------------------------------------------------------------
__global__ __launch_bounds__(256) void conv_kernel(
    const float* __restrict__ qx, const float* __restrict__ kx, const float* __restrict__ vx,
    const float* __restrict__ Wq, const float* __restrict__ Wk, const float* __restrict__ Wv,
    const float* __restrict__ bq, const float* __restrict__ bk, const float* __restrict__ bv,
    f16* __restrict__ Qh, f16* __restrict__ Kh, f16* __restrict__ Vt)
{
    const int tz = blockIdx.z;
    const float* __restrict__ x  = (tz == 0) ? qx : (tz == 1) ? kx : vx;
    const float* __restrict__ W  = (tz == 0) ? Wq : (tz == 1) ? Wk : Wv;
    const float* __restrict__ bp = (tz == 0) ? bq : (tz == 1) ? bk : bv;

    const int bh = blockIdx.y;          // b*H + h
    const int h  = bh & (H - 1);
    const int l0 = blockIdx.x * 64;
    const int tid = threadIdx.x;
    const int d   = tid & 63;           // output channel within head
    const int lg  = tid >> 6;           // 0..3, group of 16 l-positions
    const int b   = bh >> 3;

    __shared__ float xs[66 * 32];       // [l(-1..64)][ci chunk 32]
    __shared__ float wsm[96 * 65];      // [r = ci*3+t][d], pad 65

    float acc[16];
#pragma unroll
    for (int i = 0; i < 16; ++i) acc[i] = 0.0f;

    for (int c0 = 0; c0 < CIN; c0 += 32) {
        __syncthreads();
        for (int f = tid; f < 66 * 32; f += 256) {
            const int lr = f >> 5, cc = f & 31;
            const int lgl = l0 - 1 + lr;
            float val = 0.0f;
            if (lgl >= 0 && lgl < L)
                val = x[((size_t)b * L + lgl) * CIN + c0 + cc];
            xs[f] = val;
        }
        for (int f = tid; f < 64 * 96; f += 256) {
            const int dd = f / 96, rr = f - dd * 96;
            wsm[rr * 65 + dd] = W[(size_t)(h * 64 + dd) * (CIN * 3) + c0 * 3 + rr];
        }
        __syncthreads();
#pragma unroll 1
        for (int cg = 0; cg < 8; ++cg) {
            float4 xv[18];
#pragma unroll
            for (int r = 0; r < 18; ++r)
                xv[r] = *(const float4*)&xs[(lg * 16 + r) * 32 + cg * 4];
#pragma unroll
            for (int cc = 0; cc < 4; ++cc) {
                const int ci = cg * 4 + cc;
                const float w0 = wsm[(ci * 3 + 0) * 65 + d];
                const float w1 = wsm[(ci * 3 + 1) * 65 + d];
                const float w2 = wsm[(ci * 3 + 2) * 65 + d];
#pragma unroll
                for (int ll = 0; ll < 16; ++ll) {
                    acc[ll] = fmaf(w0, ((const float*)&xv[ll    ])[cc], acc[ll]);
                    acc[ll] = fmaf(w1, ((const float*)&xv[ll + 1])[cc], acc[ll]);
                    acc[ll] = fmaf(w2, ((const float*)&xv[ll + 2])[cc], acc[ll]);
                }
            }
        }
    }
    const float bias = bp[h * 64 + d];
    if (tz < 2) {
        f16* __restrict__ outp = (tz == 0) ? Qh : Kh;
#pragma unroll
        for (int ll = 0; ll < 16; ++ll) {
            const int l = l0 + lg * 16 + ll;
            outp[((size_t)bh * L + l) * 64 + d] = (f16)(acc[ll] + bias);
        }
    } else {
        f16 t[16];
#pragma unroll
        for (int ll = 0; ll < 16; ++ll) t[ll] = (f16)(acc[ll] + bias);
        float4* dst = (float4*)&Vt[((size_t)(bh * 64 + d)) * L + l0 + lg * 16];
        dst[0] = ((const float4*)t)[0];
        dst[1] = ((const float4*)t)[1];
    }
}

// ---------------------------------------------------------------------------
// Attention with f16 MFMA (16x16x32).  Per block: one (b,h), 64 q rows.
// 4 waves x 16 q-rows each.  K-tiles of 64.  Raw S -> A region, sweep-2
// normalizes in place.  All MFMA operands read row-major-over-K from LDS with
// identical per-lane offsets (k-permutation-invariant).  C/D layout:
// col = lane&15, row = (lane>>4)*4 + reg.
// ---------------------------------------------------------------------------
__global__ __launch_bounds__(256) void attn_kernel(
    const f16* __restrict__ Qh, const f16* __restrict__ Kh, const f16* __restrict__ Vt,
    const float* __restrict__ w_pos, const int* __restrict__ amask,
    const float* __restrict__ vmaskp,
    float* __restrict__ Aout, float* __restrict__ Oh)
{
    const int bh = blockIdx.y;
    const int b = bh >> 3, h = bh & 7;
    const int q0 = blockIdx.x * 64;
    const int tid = threadIdx.x;
    const int wv   = tid >> 6;
    const int lane = tid & 63;
    const int lg16 = lane & 15;
    const int lg4  = lane >> 4;

    __shared__ __align__(16) f16  smem_h[4608 * 4];   // Qs,Ks,Vs,es  (rows*72)
    __shared__ __align__(16) float Ps[64 * 66];       // pos table P[qloc][rel 0..64]
    f16* const Qs = smem_h;
    f16* const Ks = smem_h + 4608;
    f16* const Vs = smem_h + 2 * 4608;
    f16* const es = smem_h + 3 * 4608;
    f16* const wps = Ks;            // phase-A alias (80*72 spans Ks + head of Vs)

    // prefetch k-tile 0 (K rows / Vt rows, 2 x 16B per thread each)
    float4 kreg[2], vreg[2];
#pragma unroll
    for (int p = 0; p < 2; ++p) {
        const int it = tid + p * 256, row = it >> 3, ch = it & 7;
        kreg[p] = *(const float4*)&Kh[((size_t)bh * L + row) * 64 + ch * 8];
        vreg[p] = *(const float4*)&Vt[((size_t)(bh * 64 + row)) * L + ch * 8];
    }

    // stage Q tile (f16) and w_pos (f32 -> f16, rows >= 65 zero)
    for (int i = tid; i < 512; i += 256) {
        const int row = i >> 3, ch = i & 7;
        *(float4*)&Qs[row * 72 + ch * 8] =
            *(const float4*)&Qh[((size_t)bh * L + q0 + row) * 64 + ch * 8];
    }
    for (int i = tid; i < 640; i += 256) {
        const int r = i >> 3, ch = i & 7;
        f16 t[8];
        if (r < 65) {
            const float* s = w_pos + (size_t)r * 64 + ch * 8;
#pragma unroll
            for (int j = 0; j < 8; ++j) t[j] = (f16)s[j];
        } else {
#pragma unroll
            for (int j = 0; j < 8; ++j) t[j] = (f16)0.f;
        }
        *(float4*)&wps[r * 72 + ch * 8] = *(const float4*)t;
    }
    __syncthreads();

    // persistent Q A-fragments (row = wave's q row lg16, k-chunks 0/1)
    f16x8 qa[2];
#pragma unroll
    for (int kc = 0; kc < 2; ++kc)
        qa[kc] = *(const f16x8*)&Qs[(wv * 16 + lg16) * 72 + kc * 32 + lg4 * 8];

    // P[qloc][r] = Q . w_pos[r]  via MFMA (5 n-tiles of 16 cover r=0..64)
#pragma unroll
    for (int c = 0; c < 5; ++c) {
        f32x4 acc = {0.f, 0.f, 0.f, 0.f};
#pragma unroll
        for (int kc = 0; kc < 2; ++kc) {
            f16x8 wb = *(const f16x8*)&wps[(c * 16 + lg16) * 72 + kc * 32 + lg4 * 8];
            acc = __builtin_amdgcn_mfma_f32_16x16x32_f16(qa[kc], wb, acc, 0, 0, 0);
        }
        const int r = c * 16 + lg16;
        if (r < 65) {
#pragma unroll
            for (int j = 0; j < 4; ++j)
                Ps[(wv * 16 + lg4 * 4 + j) * 66 + r] = acc[j];
        }
    }

    float mrow[4], lrow[4];
#pragma unroll
    for (int j = 0; j < 4; ++j) { mrow[j] = -INFINITY; lrow[j] = 0.f; }
    f32x4 Oc[4];
#pragma unroll
    for (int c = 0; c < 4; ++c) Oc[c] = (f32x4){0.f, 0.f, 0.f, 0.f};

    const int qloc0 = wv * 16 + lg4 * 4;                  // this thread's 4 q rows
    const size_t Abase = ((size_t)bh * L + q0 + qloc0) * L;

    for (int kt = 0; kt < 16; ++kt) {
        const int kbase = kt * 64;
        __syncthreads();                                   // prev tile reads done; wps dead
#pragma unroll
        for (int p = 0; p < 2; ++p) {
            const int it = tid + p * 256, row = it >> 3, ch = it & 7;
            *(float4*)&Ks[row * 72 + ch * 8] = kreg[p];
            *(float4*)&Vs[row * 72 + ch * 8] = vreg[p];
        }
        __syncthreads();
        if (kt < 15) {                                     // T14: prefetch under compute
            const int kb2 = kbase + 64;
#pragma unroll
            for (int p = 0; p < 2; ++p) {
                const int it = tid + p * 256, row = it >> 3, ch = it & 7;
                kreg[p] = *(const float4*)&Kh[((size_t)bh * L + kb2 + row) * 64 + ch * 8];
                vreg[p] = *(const float4*)&Vt[((size_t)(bh * 64 + row)) * L + kb2 + ch * 8];
            }
        }

        // ---- S = QK^T
        f32x4 sc[4];
#pragma unroll
        for (int c = 0; c < 4; ++c) {
            sc[c] = (f32x4){0.f, 0.f, 0.f, 0.f};
#pragma unroll
            for (int kc = 0; kc < 2; ++kc) {
                f16x8 kb = *(const f16x8*)&Ks[(c * 16 + lg16) * 72 + kc * 32 + lg4 * 8];
                sc[c] = __builtin_amdgcn_mfma_f32_16x16x32_f16(qa[kc], kb, sc[c], 0, 0, 0);
            }
        }

        // ---- scale + pos + mask, raw S -> A region
        float sv[4][4];
#pragma unroll
        for (int c = 0; c < 4; ++c) {
            const int kg = kbase + c * 16 + lg16;
#pragma unroll
            for (int j = 0; j < 4; ++j) {
                const int ql = qloc0 + j;
                const int qg = q0 + ql;
                int off = kg - qg;
                off = off < -32 ? -32 : (off > 32 ? 32 : off);
                float v = sc[c][j] * 0.125f + Ps[ql * 66 + off + 32];
                if (amask[(size_t)qg * L + kg] != 0) v = -INFINITY;
                Aout[Abase + (size_t)j * L + kg] = v;
                sv[c][j] = v;
            }
        }

        // ---- online softmax (row spread over 16 lanes sharing lg4)
        float mn[4], al[4];
#pragma unroll
        for (int j = 0; j < 4; ++j) {
            float t = fmaxf(fmaxf(sv[0][j], sv[1][j]), fmaxf(sv[2][j], sv[3][j]));
            t = fmaxf(t, __shfl_xor(t, 1, 64));
            t = fmaxf(t, __shfl_xor(t, 2, 64));
            t = fmaxf(t, __shfl_xor(t, 4, 64));
            t = fmaxf(t, __shfl_xor(t, 8, 64));
            mn[j] = fmaxf(mrow[j], t);
        }
#pragma unroll
        for (int j = 0; j < 4; ++j) {
            float s = 0.f;
            if (mn[j] == -INFINITY) {
                al[j] = 1.f;
#pragma unroll
                for (int c = 0; c < 4; ++c) sv[c][j] = 0.f;
            } else {
                al[j] = __expf(mrow[j] - mn[j]);
#pragma unroll
                for (int c = 0; c < 4; ++c) { sv[c][j] = __expf(sv[c][j] - mn[j]); s += sv[c][j]; }
            }
            s += __shfl_xor(s, 1, 64);
            s += __shfl_xor(s, 2, 64);
            s += __shfl_xor(s, 4, 64);
            s += __shfl_xor(s, 8, 64);
            lrow[j] = lrow[j] * al[j] + s;
            mrow[j] = mn[j];
        }

        // ---- e -> LDS (wave-private rows), then PV
#pragma unroll
        for (int c = 0; c < 4; ++c)
#pragma unroll
            for (int j = 0; j < 4; ++j)
                es[(qloc0 + j) * 72 + c * 16 + lg16] = (f16)sv[c][j];
        asm volatile("s_waitcnt lgkmcnt(0)" ::: "memory");
        __builtin_amdgcn_sched_barrier(0);                 // rule #18: pin MFMA after wait
#pragma unroll
        for (int c = 0; c < 4; ++c)
#pragma unroll
            for (int j = 0; j < 4; ++j)
                Oc[c][j] *= al[j];

        f16x8 ea[2];
#pragma unroll
        for (int kc = 0; kc < 2; ++kc)
            ea[kc] = *(const f16x8*)&es[(wv * 16 + lg16) * 72 + kc * 32 + lg4 * 8];
#pragma unroll
        for (int c = 0; c < 4; ++c)
#pragma unroll
            for (int kc = 0; kc < 2; ++kc) {
                f16x8 vb = *(const f16x8*)&Vs[(c * 16 + lg16) * 72 + kc * 32 + lg4 * 8];
                Oc[c] = __builtin_amdgcn_mfma_f32_16x16x32_f16(ea[kc], vb, Oc[c], 0, 0, 0);
            }
    }

    float il[4];
#pragma unroll
    for (int j = 0; j < 4; ++j) il[j] = lrow[j] > 0.f ? 1.f / lrow[j] : 0.f;
#pragma unroll
    for (int c = 0; c < 4; ++c)
#pragma unroll
        for (int j = 0; j < 4; ++j)
            Oh[((size_t)b * L + q0 + qloc0 + j) * DOUT + h * 64 + c * 16 + lg16] =
                Oc[c][j] * il[j];

    // ---- sweep 2: normalize A in place (same-thread addresses only)
    const float vm = vmaskp[0];
    for (int kt = 0; kt < 16; ++kt) {
#pragma unroll
        for (int c = 0; c < 4; ++c) {
            const int kg = kt * 64 + c * 16 + lg16;
#pragma unroll
            for (int j = 0; j < 4; ++j) {
                const size_t ad = Abase + (size_t)j * L + kg;
                const float s = Aout[ad];
                float a = (mrow[j] == -INFINITY) ? 0.f : __expf(s - mrow[j]) * il[j];
                if (!(a > vm)) a = 0.f;
                Aout[ad] = a;
            }
        }
    }
}

// ---------------------------------------------------------------------------
// FC: out[row][j] = O[row][:] . Wfc[j][:] + bfc[j]   rows = B*L  (fp32)
// ---------------------------------------------------------------------------
__global__ __launch_bounds__(256) void fc_kernel(
    const float* __restrict__ Ohp, const float* __restrict__ Wfc,
    const float* __restrict__ bfc, float* __restrict__ outp)
{
    __shared__ float Os[64 * 68];
    __shared__ float Ws[64 * 68];
    const int r0 = blockIdx.x * 64;
    const int j0 = blockIdx.y * 64;
    const int tid = threadIdx.x;
    const int rg = tid >> 4, cg = tid & 15;

    float acc[4][4];
#pragma unroll
    for (int r = 0; r < 4; ++r)
#pragma unroll
        for (int c = 0; c < 4; ++c) acc[r][c] = 0.0f;

    for (int kc = 0; kc < DOUT; kc += 64) {
        __syncthreads();
        for (int i4 = tid; i4 < 64 * 16; i4 += 256) {
            const int r = i4 >> 4, c4 = i4 & 15;
            *(float4*)&Os[r * 68 + c4 * 4] =
                *(const float4*)&Ohp[(size_t)(r0 + r) * DOUT + kc + c4 * 4];
            *(float4*)&Ws[r * 68 + c4 * 4] =
                *(const float4*)&Wfc[(size_t)(j0 + r) * DOUT + kc + c4 * 4];
        }
        __syncthreads();
#pragma unroll 4
        for (int i = 0; i < 16; ++i) {
            float4 av[4], wv4[4];
#pragma unroll
            for (int r = 0; r < 4; ++r) av[r] = *(const float4*)&Os[(rg * 4 + r) * 68 + i * 4];
#pragma unroll
            for (int c = 0; c < 4; ++c) wv4[c] = *(const float4*)&Ws[(cg * 4 + c) * 68 + i * 4];
#pragma unroll
            for (int r = 0; r < 4; ++r)
#pragma unroll
                for (int c = 0; c < 4; ++c) {
                    acc[r][c] = fmaf(av[r].x, wv4[c].x, acc[r][c]);
                    acc[r][c] = fmaf(av[r].y, wv4[c].y, acc[r][c]);
                    acc[r][c] = fmaf(av[r].z, wv4[c].z, acc[r][c]);
                    acc[r][c] = fmaf(av[r].w, wv4[c].w, acc[r][c]);
                }
        }
    }
    const float4 bias = *(const float4*)&bfc[j0 + cg * 4];
#pragma unroll
    for (int r = 0; r < 4; ++r) {
        float4 o = make_float4(acc[r][0] + bias.x, acc[r][1] + bias.y,
                               acc[r][2] + bias.z, acc[r][3] + bias.w);
        *(float4*)&outp[(size_t)(r0 + rg * 4 + r) * DOUT + j0 + cg * 4] = o;
    }
}

// ---------------------------------------------------------------------------
extern "C" void kernel_launch(void* const* d_in, const int* in_sizes, int n_in,
                              void* d_out, int out_size, void* d_ws, size_t ws_size,
                              hipStream_t stream) {
    const float* q    = (const float*)d_in[0];
    const float* k    = (const float*)d_in[1];
    const float* v    = (const float*)d_in[2];
    const float* Wq   = (const float*)d_in[3];
    const float* bq   = (const float*)d_in[4];
    const float* Wk   = (const float*)d_in[5];
    const float* bk   = (const float*)d_in[6];
    const float* Wv   = (const float*)d_in[7];
    const float* bv   = (const float*)d_in[8];
    const float* Wfc  = (const float*)d_in[9];
    const float* bfc  = (const float*)d_in[10];
    const float* wpos = (const float*)d_in[11];
    const int*   amsk = (const int*)d_in[12];
    const float* vmsk = (const float*)d_in[13];

    f16* Qh = (f16*)d_ws;                                   // [bh][l][64] f16
    f16* Kh = Qh + (size_t)2097152;
    f16* Vt = Kh + (size_t)2097152;                          // [b*512+co][l] f16
    float* Oh = (float*)(Vt + (size_t)2097152);              // [b][l][512] f32

    float* outp = (float*)d_out;                             // [B][L][512]
    float* Aout = outp + (size_t)B * L * DOUT;               // [B][H][L][L]

    conv_kernel<<<dim3(L / 64, B * H, 3), 256, 0, stream>>>(
        q, k, v, Wq, Wk, Wv, bq, bk, bv, Qh, Kh, Vt);
    attn_kernel<<<dim3(L / 64, B * H), 256, 0, stream>>>(
        Qh, Kh, Vt, wpos, amsk, vmsk, Aout, Oh);
    fc_kernel<<<dim3(B * L / 64, DOUT / 64), 256, 0, stream>>>(
        Oh, Wfc, bfc, outp);
}

// Round 11
// 432.833 us; speedup vs baseline: 2.5554x; 1.5191x over previous
//
#include <hip/hip_runtime.h>
#include <math.h>

typedef _Float16 f16;
typedef _Float16 f16x4 __attribute__((ext_vector_type(4)));
typedef _Float16 f16x8 __attribute__((ext_vector_type(8)));
typedef float f32x4 __attribute__((ext_vector_type(4)));

constexpr int B    = 4;
constexpr int L    = 1024;
constexpr int CIN  = 256;
constexpr int H    = 8;
constexpr int DOUT = 512;

// ---------------------------------------------------------------------------
// Pack conv weights t-major: Wp[proj][co][t*256+ci] = f16(W[co][ci*3+t])
// grid (512, 3), block 256 (thread = ci).
// ---------------------------------------------------------------------------
__global__ void pack_kernel(const float* __restrict__ Wq, const float* __restrict__ Wk,
                            const float* __restrict__ Wv, f16* __restrict__ Wp)
{
    const int proj = blockIdx.y;
    const int co   = blockIdx.x;
    const int ci   = threadIdx.x;
    const float* W = (proj == 0) ? Wq : (proj == 1) ? Wk : Wv;
    f16* dst = Wp + ((size_t)proj * 512 + co) * 768;
    const float* src = W + (size_t)co * 768 + ci * 3;
    dst[0 * 256 + ci] = (f16)src[0];
    dst[1 * 256 + ci] = (f16)src[1];
    dst[2 * 256 + ci] = (f16)src[2];
}

// ---------------------------------------------------------------------------
// Conv1d as MFMA GEMM.  C[l][co] = sum_k A[l][k]*Bw[co][k], k = t*256+ci,
// A[l][t*256+ci] = x[l+t-1][ci]  (zeros at b-boundary).  Split precision:
// x = hi+lo f16 (2 MFMA chains) keeps fp32-quality output; W single f16.
// grid (32 Mtiles, 4 Ntiles, 3 proj), block 256 (4 waves, 2x2 of 64x64).
// Epilogue via LDS transpose for coalesced stores:
//   Q,K -> [bh][l][64] f16 ; V -> Vt[b*512+co][l] f16.
// ---------------------------------------------------------------------------
__global__ __launch_bounds__(256) void convg_kernel(
    const float* __restrict__ qx, const float* __restrict__ kx, const float* __restrict__ vx,
    const f16* __restrict__ Wp,
    const float* __restrict__ bq, const float* __restrict__ bk, const float* __restrict__ bv,
    f16* __restrict__ Qh, f16* __restrict__ Kh, f16* __restrict__ Vt)
{
    const int proj = blockIdx.z;
    const float* __restrict__ x    = (proj == 0) ? qx : (proj == 1) ? kx : vx;
    const float* __restrict__ bias = (proj == 0) ? bq : (proj == 1) ? bk : bv;

    const int mt = blockIdx.x;            // 0..31 : M tile (b, l0)
    const int b  = mt >> 3;
    const int l0 = (mt & 7) * 128;
    const int nb = blockIdx.y * 128;      // co base
    const int tid  = threadIdx.x;
    const int wvid = tid >> 6;
    const int lane = tid & 63;
    const int lg16 = lane & 15;
    const int lg4  = lane >> 4;
    const int wr = wvid >> 1, wc = wvid & 1;   // 64x64 quadrant

    __shared__ __align__(16) f16 smem[3 * 128 * 72];
    f16* const Ah = smem;                  // [128][72] x_hi
    f16* const Al = smem + 128 * 72;       // [128][72] x_lo
    f16* const Bs = smem + 2 * 128 * 72;   // [128][72] W
    f16* const Ct = smem;                  // epilogue alias [128][136] (34816B <= 55296B)

    f32x4 acc[4][4];
#pragma unroll
    for (int mi = 0; mi < 4; ++mi)
#pragma unroll
        for (int ni = 0; ni < 4; ++ni) acc[mi][ni] = (f32x4){0.f, 0.f, 0.f, 0.f};

    const int r_st = tid >> 1;             // staging row 0..127
    const int c_st = (tid & 1) * 32;       // staging col offset (elements)

    for (int kc = 0; kc < 12; ++kc) {
        const int t = kc >> 2, ci0 = (kc & 3) << 6;
        __syncthreads();                   // prev-chunk LDS reads done
        {   // ---- stage A (x -> hi/lo f16)
            const int l = l0 + r_st + t - 1;
            const bool ok = (l >= 0) && (l < L);
            const float* sx = x + ((size_t)b * L + (ok ? l : 0)) * CIN + ci0 + c_st;
#pragma unroll
            for (int g = 0; g < 4; ++g) {
                float4 v0 = make_float4(0.f, 0.f, 0.f, 0.f), v1 = v0;
                if (ok) { v0 = ((const float4*)sx)[g * 2]; v1 = ((const float4*)sx)[g * 2 + 1]; }
                float vv[8] = {v0.x, v0.y, v0.z, v0.w, v1.x, v1.y, v1.z, v1.w};
                f16 h8[8], l8[8];
#pragma unroll
                for (int i = 0; i < 8; ++i) {
                    h8[i] = (f16)vv[i];
                    l8[i] = (f16)(vv[i] - (float)h8[i]);
                }
                *(float4*)&Ah[r_st * 72 + c_st + g * 8] = *(const float4*)h8;
                *(float4*)&Al[r_st * 72 + c_st + g * 8] = *(const float4*)l8;
            }
        }
        {   // ---- stage B (packed W, f16 direct)
            const f16* sw = Wp + ((size_t)proj * 512 + nb + r_st) * 768 + kc * 64 + c_st;
#pragma unroll
            for (int g = 0; g < 4; ++g)
                *(float4*)&Bs[r_st * 72 + c_st + g * 8] = ((const float4*)sw)[g];
        }
        __syncthreads();

#pragma unroll
        for (int ks = 0; ks < 2; ++ks) {
            f16x8 bb[4];
#pragma unroll
            for (int ni = 0; ni < 4; ++ni)
                bb[ni] = *(const f16x8*)&Bs[(wc * 64 + ni * 16 + lg16) * 72 + ks * 32 + lg4 * 8];
#pragma unroll
            for (int mi = 0; mi < 4; ++mi) {
                const f16x8 ah = *(const f16x8*)&Ah[(wr * 64 + mi * 16 + lg16) * 72 + ks * 32 + lg4 * 8];
                const f16x8 al = *(const f16x8*)&Al[(wr * 64 + mi * 16 + lg16) * 72 + ks * 32 + lg4 * 8];
#pragma unroll
                for (int ni = 0; ni < 4; ++ni) {
                    acc[mi][ni] = __builtin_amdgcn_mfma_f32_16x16x32_f16(ah, bb[ni], acc[mi][ni], 0, 0, 0);
                    acc[mi][ni] = __builtin_amdgcn_mfma_f32_16x16x32_f16(al, bb[ni], acc[mi][ni], 0, 0, 0);
                }
            }
        }
    }

    // ---- epilogue: bias, LDS re-tile, coalesced stores
    float bvv[4];
#pragma unroll
    for (int ni = 0; ni < 4; ++ni) bvv[ni] = bias[nb + wc * 64 + ni * 16 + lg16];
    __syncthreads();                       // K-loop LDS reads done; smem reusable

    if (proj < 2) {
        // natural orientation Ct[l][co]
#pragma unroll
        for (int mi = 0; mi < 4; ++mi)
#pragma unroll
            for (int ni = 0; ni < 4; ++ni)
#pragma unroll
                for (int jr = 0; jr < 4; ++jr)
                    Ct[(wr * 64 + mi * 16 + lg4 * 4 + jr) * 136 + wc * 64 + ni * 16 + lg16] =
                        (f16)(acc[mi][ni][jr] + bvv[ni]);
        __syncthreads();
        f16* __restrict__ outp = (proj == 0) ? Qh : Kh;
        const int r = tid >> 1, hh = tid & 1;
        const int bh = b * 8 + (nb >> 6) + hh;
        float4* dst = (float4*)&outp[((size_t)bh * L + l0 + r) * 64];
        const float4* srcp = (const float4*)&Ct[r * 136 + hh * 64];
#pragma unroll
        for (int i = 0; i < 8; ++i) dst[i] = srcp[i];   // 64 f16 = 8 x float4
    } else {
        // transposed Ct[co][l]
#pragma unroll
        for (int mi = 0; mi < 4; ++mi)
#pragma unroll
            for (int ni = 0; ni < 4; ++ni) {
                f16x4 pk = {(f16)(acc[mi][ni][0] + bvv[ni]), (f16)(acc[mi][ni][1] + bvv[ni]),
                            (f16)(acc[mi][ni][2] + bvv[ni]), (f16)(acc[mi][ni][3] + bvv[ni])};
                *(f16x4*)&Ct[(wc * 64 + ni * 16 + lg16) * 136 + wr * 64 + mi * 16 + lg4 * 4] = pk;
            }
        __syncthreads();
        const int r = tid >> 1, hh = tid & 1;          // r = co within tile
        float4* dst = (float4*)&Vt[((size_t)b * 512 + nb + r) * L + l0 + hh * 64];
        const float4* srcp = (const float4*)&Ct[r * 136 + hh * 64];
#pragma unroll
        for (int i = 0; i < 8; ++i) dst[i] = srcp[i];   // 64 f16 = 8 x float4
    }
}

// ---------------------------------------------------------------------------
// Attention with f16 MFMA (16x16x32).  Unchanged from round 5 except Oh -> f16.
// ---------------------------------------------------------------------------
__global__ __launch_bounds__(256) void attn_kernel(
    const f16* __restrict__ Qh, const f16* __restrict__ Kh, const f16* __restrict__ Vt,
    const float* __restrict__ w_pos, const int* __restrict__ amask,
    const float* __restrict__ vmaskp,
    float* __restrict__ Aout, f16* __restrict__ Oh)
{
    const int bh = blockIdx.y;
    const int b = bh >> 3, h = bh & 7;
    const int q0 = blockIdx.x * 64;
    const int tid = threadIdx.x;
    const int wv   = tid >> 6;
    const int lane = tid & 63;
    const int lg16 = lane & 15;
    const int lg4  = lane >> 4;

    __shared__ __align__(16) f16  smem_h[4608 * 4];   // Qs,Ks,Vs,es  (rows*72)
    __shared__ __align__(16) float Ps[64 * 66];       // pos table P[qloc][rel 0..64]
    f16* const Qs = smem_h;
    f16* const Ks = smem_h + 4608;
    f16* const Vs = smem_h + 2 * 4608;
    f16* const es = smem_h + 3 * 4608;
    f16* const wps = Ks;            // phase-A alias (80*72 spans Ks + head of Vs)

    float4 kreg[2], vreg[2];
#pragma unroll
    for (int p = 0; p < 2; ++p) {
        const int it = tid + p * 256, row = it >> 3, ch = it & 7;
        kreg[p] = *(const float4*)&Kh[((size_t)bh * L + row) * 64 + ch * 8];
        vreg[p] = *(const float4*)&Vt[((size_t)(bh * 64 + row)) * L + ch * 8];
    }

    for (int i = tid; i < 512; i += 256) {
        const int row = i >> 3, ch = i & 7;
        *(float4*)&Qs[row * 72 + ch * 8] =
            *(const float4*)&Qh[((size_t)bh * L + q0 + row) * 64 + ch * 8];
    }
    for (int i = tid; i < 640; i += 256) {
        const int r = i >> 3, ch = i & 7;
        f16 t[8];
        if (r < 65) {
            const float* s = w_pos + (size_t)r * 64 + ch * 8;
#pragma unroll
            for (int j = 0; j < 8; ++j) t[j] = (f16)s[j];
        } else {
#pragma unroll
            for (int j = 0; j < 8; ++j) t[j] = (f16)0.f;
        }
        *(float4*)&wps[r * 72 + ch * 8] = *(const float4*)t;
    }
    __syncthreads();

    f16x8 qa[2];
#pragma unroll
    for (int kc = 0; kc < 2; ++kc)
        qa[kc] = *(const f16x8*)&Qs[(wv * 16 + lg16) * 72 + kc * 32 + lg4 * 8];

#pragma unroll
    for (int c = 0; c < 5; ++c) {
        f32x4 acc = {0.f, 0.f, 0.f, 0.f};
#pragma unroll
        for (int kc = 0; kc < 2; ++kc) {
            f16x8 wb = *(const f16x8*)&wps[(c * 16 + lg16) * 72 + kc * 32 + lg4 * 8];
            acc = __builtin_amdgcn_mfma_f32_16x16x32_f16(qa[kc], wb, acc, 0, 0, 0);
        }
        const int r = c * 16 + lg16;
        if (r < 65) {
#pragma unroll
            for (int j = 0; j < 4; ++j)
                Ps[(wv * 16 + lg4 * 4 + j) * 66 + r] = acc[j];
        }
    }

    float mrow[4], lrow[4];
#pragma unroll
    for (int j = 0; j < 4; ++j) { mrow[j] = -INFINITY; lrow[j] = 0.f; }
    f32x4 Oc[4];
#pragma unroll
    for (int c = 0; c < 4; ++c) Oc[c] = (f32x4){0.f, 0.f, 0.f, 0.f};

    const int qloc0 = wv * 16 + lg4 * 4;
    const size_t Abase = ((size_t)bh * L + q0 + qloc0) * L;

    for (int kt = 0; kt < 16; ++kt) {
        const int kbase = kt * 64;
        __syncthreads();
#pragma unroll
        for (int p = 0; p < 2; ++p) {
            const int it = tid + p * 256, row = it >> 3, ch = it & 7;
            *(float4*)&Ks[row * 72 + ch * 8] = kreg[p];
            *(float4*)&Vs[row * 72 + ch * 8] = vreg[p];
        }
        __syncthreads();
        if (kt < 15) {
            const int kb2 = kbase + 64;
#pragma unroll
            for (int p = 0; p < 2; ++p) {
                const int it = tid + p * 256, row = it >> 3, ch = it & 7;
                kreg[p] = *(const float4*)&Kh[((size_t)bh * L + kb2 + row) * 64 + ch * 8];
                vreg[p] = *(const float4*)&Vt[((size_t)(bh * 64 + row)) * L + kb2 + ch * 8];
            }
        }

        f32x4 sc[4];
#pragma unroll
        for (int c = 0; c < 4; ++c) {
            sc[c] = (f32x4){0.f, 0.f, 0.f, 0.f};
#pragma unroll
            for (int kc = 0; kc < 2; ++kc) {
                f16x8 kb = *(const f16x8*)&Ks[(c * 16 + lg16) * 72 + kc * 32 + lg4 * 8];
                sc[c] = __builtin_amdgcn_mfma_f32_16x16x32_f16(qa[kc], kb, sc[c], 0, 0, 0);
            }
        }

        float sv[4][4];
#pragma unroll
        for (int c = 0; c < 4; ++c) {
            const int kg = kbase + c * 16 + lg16;
#pragma unroll
            for (int j = 0; j < 4; ++j) {
                const int ql = qloc0 + j;
                const int qg = q0 + ql;
                int off = kg - qg;
                off = off < -32 ? -32 : (off > 32 ? 32 : off);
                float v = sc[c][j] * 0.125f + Ps[ql * 66 + off + 32];
                if (amask[(size_t)qg * L + kg] != 0) v = -INFINITY;
                Aout[Abase + (size_t)j * L + kg] = v;
                sv[c][j] = v;
            }
        }

        float mn[4], al[4];
#pragma unroll
        for (int j = 0; j < 4; ++j) {
            float t = fmaxf(fmaxf(sv[0][j], sv[1][j]), fmaxf(sv[2][j], sv[3][j]));
            t = fmaxf(t, __shfl_xor(t, 1, 64));
            t = fmaxf(t, __shfl_xor(t, 2, 64));
            t = fmaxf(t, __shfl_xor(t, 4, 64));
            t = fmaxf(t, __shfl_xor(t, 8, 64));
            mn[j] = fmaxf(mrow[j], t);
        }
#pragma unroll
        for (int j = 0; j < 4; ++j) {
            float s = 0.f;
            if (mn[j] == -INFINITY) {
                al[j] = 1.f;
#pragma unroll
                for (int c = 0; c < 4; ++c) sv[c][j] = 0.f;
            } else {
                al[j] = __expf(mrow[j] - mn[j]);
#pragma unroll
                for (int c = 0; c < 4; ++c) { sv[c][j] = __expf(sv[c][j] - mn[j]); s += sv[c][j]; }
            }
            s += __shfl_xor(s, 1, 64);
            s += __shfl_xor(s, 2, 64);
            s += __shfl_xor(s, 4, 64);
            s += __shfl_xor(s, 8, 64);
            lrow[j] = lrow[j] * al[j] + s;
            mrow[j] = mn[j];
        }

#pragma unroll
        for (int c = 0; c < 4; ++c)
#pragma unroll
            for (int j = 0; j < 4; ++j)
                es[(qloc0 + j) * 72 + c * 16 + lg16] = (f16)sv[c][j];
        asm volatile("s_waitcnt lgkmcnt(0)" ::: "memory");
        __builtin_amdgcn_sched_barrier(0);
#pragma unroll
        for (int c = 0; c < 4; ++c)
#pragma unroll
            for (int j = 0; j < 4; ++j)
                Oc[c][j] *= al[j];

        f16x8 ea[2];
#pragma unroll
        for (int kc = 0; kc < 2; ++kc)
            ea[kc] = *(const f16x8*)&es[(wv * 16 + lg16) * 72 + kc * 32 + lg4 * 8];
#pragma unroll
        for (int c = 0; c < 4; ++c)
#pragma unroll
            for (int kc = 0; kc < 2; ++kc) {
                f16x8 vb = *(const f16x8*)&Vs[(c * 16 + lg16) * 72 + kc * 32 + lg4 * 8];
                Oc[c] = __builtin_amdgcn_mfma_f32_16x16x32_f16(ea[kc], vb, Oc[c], 0, 0, 0);
            }
    }

    float il[4];
#pragma unroll
    for (int j = 0; j < 4; ++j) il[j] = lrow[j] > 0.f ? 1.f / lrow[j] : 0.f;
#pragma unroll
    for (int c = 0; c < 4; ++c)
#pragma unroll
        for (int j = 0; j < 4; ++j)
            Oh[((size_t)b * L + q0 + qloc0 + j) * DOUT + h * 64 + c * 16 + lg16] =
                (f16)(Oc[c][j] * il[j]);

    const float vm = vmaskp[0];
    for (int kt = 0; kt < 16; ++kt) {
#pragma unroll
        for (int c = 0; c < 4; ++c) {
            const int kg = kt * 64 + c * 16 + lg16;
#pragma unroll
            for (int j = 0; j < 4; ++j) {
                const size_t ad = Abase + (size_t)j * L + kg;
                const float s = Aout[ad];
                float a = (mrow[j] == -INFINITY) ? 0.f : __expf(s - mrow[j]) * il[j];
                if (!(a > vm)) a = 0.f;
                Aout[ad] = a;
            }
        }
    }
}

// ---------------------------------------------------------------------------
// FC as f16 MFMA GEMM: out[row][j] = Oh[row][:].Wfc[j][:] + bfc[j]
// grid (32, 4), block 256.  A = Oh f16 direct; B = Wfc f32 -> f16 on stage.
// ---------------------------------------------------------------------------
__global__ __launch_bounds__(256) void fcg_kernel(
    const f16* __restrict__ Ohp, const float* __restrict__ Wfc,
    const float* __restrict__ bfc, float* __restrict__ outp)
{
    const int Mb = blockIdx.x * 128;
    const int Nb = blockIdx.y * 128;
    const int tid  = threadIdx.x;
    const int wvid = tid >> 6;
    const int lane = tid & 63;
    const int lg16 = lane & 15;
    const int lg4  = lane >> 4;
    const int wr = wvid >> 1, wc = wvid & 1;

    __shared__ __align__(16) f16 As[128 * 72];
    __shared__ __align__(16) f16 Bs[128 * 72];

    f32x4 acc[4][4];
#pragma unroll
    for (int mi = 0; mi < 4; ++mi)
#pragma unroll
        for (int ni = 0; ni < 4; ++ni) acc[mi][ni] = (f32x4){0.f, 0.f, 0.f, 0.f};

    const int r_st = tid >> 1;
    const int c_st = (tid & 1) * 32;

    for (int kc = 0; kc < 8; ++kc) {
        __syncthreads();
        {   // A: Oh f16 direct
            const f16* s = Ohp + (size_t)(Mb + r_st) * DOUT + kc * 64 + c_st;
#pragma unroll
            for (int g = 0; g < 4; ++g)
                *(float4*)&As[r_st * 72 + c_st + g * 8] = ((const float4*)s)[g];
        }
        {   // B: Wfc f32 -> f16
            const float* s = Wfc + (size_t)(Nb + r_st) * DOUT + kc * 64 + c_st;
#pragma unroll
            for (int g = 0; g < 4; ++g) {
                float4 v0 = ((const float4*)s)[g * 2];
                float4 v1 = ((const float4*)s)[g * 2 + 1];
                f16 t[8] = {(f16)v0.x, (f16)v0.y, (f16)v0.z, (f16)v0.w,
                            (f16)v1.x, (f16)v1.y, (f16)v1.z, (f16)v1.w};
                *(float4*)&Bs[r_st * 72 + c_st + g * 8] = *(const float4*)t;
            }
        }
        __syncthreads();

#pragma unroll
        for (int ks = 0; ks < 2; ++ks) {
            f16x8 bb[4];
#pragma unroll
            for (int ni = 0; ni < 4; ++ni)
                bb[ni] = *(const f16x8*)&Bs[(wc * 64 + ni * 16 + lg16) * 72 + ks * 32 + lg4 * 8];
#pragma unroll
            for (int mi = 0; mi < 4; ++mi) {
                const f16x8 aa = *(const f16x8*)&As[(wr * 64 + mi * 16 + lg16) * 72 + ks * 32 + lg4 * 8];
#pragma unroll
                for (int ni = 0; ni < 4; ++ni)
                    acc[mi][ni] = __builtin_amdgcn_mfma_f32_16x16x32_f16(aa, bb[ni], acc[mi][ni], 0, 0, 0);
            }
        }
    }

#pragma unroll
    for (int ni = 0; ni < 4; ++ni) {
        const int col = Nb + wc * 64 + ni * 16 + lg16;
        const float bv = bfc[col];
#pragma unroll
        for (int mi = 0; mi < 4; ++mi) {
            const int row0 = Mb + wr * 64 + mi * 16 + lg4 * 4;
#pragma unroll
            for (int jr = 0; jr < 4; ++jr)
                outp[(size_t)(row0 + jr) * DOUT + col] = acc[mi][ni][jr] + bv;
        }
    }
}

// ---------------------------------------------------------------------------
extern "C" void kernel_launch(void* const* d_in, const int* in_sizes, int n_in,
                              void* d_out, int out_size, void* d_ws, size_t ws_size,
                              hipStream_t stream) {
    const float* q    = (const float*)d_in[0];
    const float* k    = (const float*)d_in[1];
    const float* v    = (const float*)d_in[2];
    const float* Wq   = (const float*)d_in[3];
    const float* bq   = (const float*)d_in[4];
    const float* Wk   = (const float*)d_in[5];
    const float* bk   = (const float*)d_in[6];
    const float* Wv   = (const float*)d_in[7];
    const float* bv   = (const float*)d_in[8];
    const float* Wfc  = (const float*)d_in[9];
    const float* bfc  = (const float*)d_in[10];
    const float* wpos = (const float*)d_in[11];
    const int*   amsk = (const int*)d_in[12];
    const float* vmsk = (const float*)d_in[13];

    f16* Qh  = (f16*)d_ws;                        // [bh][l][64]
    f16* Kh  = Qh  + (size_t)2097152;
    f16* Vt  = Kh  + (size_t)2097152;             // [b*512+co][l]
    f16* Ohh = Vt  + (size_t)2097152;             // [b][l][512]
    f16* Wp  = Ohh + (size_t)2097152;             // [3][512][768]

    float* outp = (float*)d_out;                  // [B][L][512]
    float* Aout = outp + (size_t)B * L * DOUT;    // [B][H][L][L]

    pack_kernel<<<dim3(512, 3), 256, 0, stream>>>(Wq, Wk, Wv, Wp);
    convg_kernel<<<dim3(32, 4, 3), 256, 0, stream>>>(
        q, k, v, Wp, bq, bk, bv, Qh, Kh, Vt);
    attn_kernel<<<dim3(L / 64, B * H), 256, 0, stream>>>(
        Qh, Kh, Vt, wpos, amsk, vmsk, Aout, Ohh);
    fcg_kernel<<<dim3(32, 4), 256, 0, stream>>>(
        Ohh, Wfc, bfc, outp);
}

// Round 12
// 388.483 us; speedup vs baseline: 2.8471x; 1.1142x over previous
//
#include <hip/hip_runtime.h>
#include <math.h>

typedef _Float16 f16;
typedef _Float16 f16x4 __attribute__((ext_vector_type(4)));
typedef _Float16 f16x8 __attribute__((ext_vector_type(8)));
typedef float f32x4 __attribute__((ext_vector_type(4)));

constexpr int B    = 4;
constexpr int L    = 1024;
constexpr int CIN  = 256;
constexpr int H    = 8;
constexpr int DOUT = 512;

// ---------------------------------------------------------------------------
// Pack conv weights t-major: Wp[proj][co][t*256+ci] = f16(W[co][ci*3+t])
// ---------------------------------------------------------------------------
__global__ void pack_kernel(const float* __restrict__ Wq, const float* __restrict__ Wk,
                            const float* __restrict__ Wv, f16* __restrict__ Wp)
{
    const int proj = blockIdx.y;
    const int co   = blockIdx.x;
    const int ci   = threadIdx.x;
    const float* W = (proj == 0) ? Wq : (proj == 1) ? Wk : Wv;
    f16* dst = Wp + ((size_t)proj * 512 + co) * 768;
    const float* src = W + (size_t)co * 768 + ci * 3;
    dst[0 * 256 + ci] = (f16)src[0];
    dst[1 * 256 + ci] = (f16)src[1];
    dst[2 * 256 + ci] = (f16)src[2];
}

// ---------------------------------------------------------------------------
// Conv1d as MFMA GEMM (unchanged from round 11 — passed, 282 -> ~? us).
// ---------------------------------------------------------------------------
__global__ __launch_bounds__(256) void convg_kernel(
    const float* __restrict__ qx, const float* __restrict__ kx, const float* __restrict__ vx,
    const f16* __restrict__ Wp,
    const float* __restrict__ bq, const float* __restrict__ bk, const float* __restrict__ bv,
    f16* __restrict__ Qh, f16* __restrict__ Kh, f16* __restrict__ Vt)
{
    const int proj = blockIdx.z;
    const float* __restrict__ x    = (proj == 0) ? qx : (proj == 1) ? kx : vx;
    const float* __restrict__ bias = (proj == 0) ? bq : (proj == 1) ? bk : bv;

    const int mt = blockIdx.x;
    const int b  = mt >> 3;
    const int l0 = (mt & 7) * 128;
    const int nb = blockIdx.y * 128;
    const int tid  = threadIdx.x;
    const int wvid = tid >> 6;
    const int lane = tid & 63;
    const int lg16 = lane & 15;
    const int lg4  = lane >> 4;
    const int wr = wvid >> 1, wc = wvid & 1;

    __shared__ __align__(16) f16 smem[3 * 128 * 72];
    f16* const Ah = smem;
    f16* const Al = smem + 128 * 72;
    f16* const Bs = smem + 2 * 128 * 72;
    f16* const Ct = smem;

    f32x4 acc[4][4];
#pragma unroll
    for (int mi = 0; mi < 4; ++mi)
#pragma unroll
        for (int ni = 0; ni < 4; ++ni) acc[mi][ni] = (f32x4){0.f, 0.f, 0.f, 0.f};

    const int r_st = tid >> 1;
    const int c_st = (tid & 1) * 32;

    for (int kc = 0; kc < 12; ++kc) {
        const int t = kc >> 2, ci0 = (kc & 3) << 6;
        __syncthreads();
        {
            const int l = l0 + r_st + t - 1;
            const bool ok = (l >= 0) && (l < L);
            const float* sx = x + ((size_t)b * L + (ok ? l : 0)) * CIN + ci0 + c_st;
#pragma unroll
            for (int g = 0; g < 4; ++g) {
                float4 v0 = make_float4(0.f, 0.f, 0.f, 0.f), v1 = v0;
                if (ok) { v0 = ((const float4*)sx)[g * 2]; v1 = ((const float4*)sx)[g * 2 + 1]; }
                float vv[8] = {v0.x, v0.y, v0.z, v0.w, v1.x, v1.y, v1.z, v1.w};
                f16 h8[8], l8[8];
#pragma unroll
                for (int i = 0; i < 8; ++i) {
                    h8[i] = (f16)vv[i];
                    l8[i] = (f16)(vv[i] - (float)h8[i]);
                }
                *(float4*)&Ah[r_st * 72 + c_st + g * 8] = *(const float4*)h8;
                *(float4*)&Al[r_st * 72 + c_st + g * 8] = *(const float4*)l8;
            }
        }
        {
            const f16* sw = Wp + ((size_t)proj * 512 + nb + r_st) * 768 + kc * 64 + c_st;
#pragma unroll
            for (int g = 0; g < 4; ++g)
                *(float4*)&Bs[r_st * 72 + c_st + g * 8] = ((const float4*)sw)[g];
        }
        __syncthreads();

#pragma unroll
        for (int ks = 0; ks < 2; ++ks) {
            f16x8 bb[4];
#pragma unroll
            for (int ni = 0; ni < 4; ++ni)
                bb[ni] = *(const f16x8*)&Bs[(wc * 64 + ni * 16 + lg16) * 72 + ks * 32 + lg4 * 8];
#pragma unroll
            for (int mi = 0; mi < 4; ++mi) {
                const f16x8 ah = *(const f16x8*)&Ah[(wr * 64 + mi * 16 + lg16) * 72 + ks * 32 + lg4 * 8];
                const f16x8 al = *(const f16x8*)&Al[(wr * 64 + mi * 16 + lg16) * 72 + ks * 32 + lg4 * 8];
#pragma unroll
                for (int ni = 0; ni < 4; ++ni) {
                    acc[mi][ni] = __builtin_amdgcn_mfma_f32_16x16x32_f16(ah, bb[ni], acc[mi][ni], 0, 0, 0);
                    acc[mi][ni] = __builtin_amdgcn_mfma_f32_16x16x32_f16(al, bb[ni], acc[mi][ni], 0, 0, 0);
                }
            }
        }
    }

    float bvv[4];
#pragma unroll
    for (int ni = 0; ni < 4; ++ni) bvv[ni] = bias[nb + wc * 64 + ni * 16 + lg16];
    __syncthreads();

    if (proj < 2) {
#pragma unroll
        for (int mi = 0; mi < 4; ++mi)
#pragma unroll
            for (int ni = 0; ni < 4; ++ni)
#pragma unroll
                for (int jr = 0; jr < 4; ++jr)
                    Ct[(wr * 64 + mi * 16 + lg4 * 4 + jr) * 136 + wc * 64 + ni * 16 + lg16] =
                        (f16)(acc[mi][ni][jr] + bvv[ni]);
        __syncthreads();
        f16* __restrict__ outp = (proj == 0) ? Qh : Kh;
        const int r = tid >> 1, hh = tid & 1;
        const int bh = b * 8 + (nb >> 6) + hh;
        float4* dst = (float4*)&outp[((size_t)bh * L + l0 + r) * 64];
        const float4* srcp = (const float4*)&Ct[r * 136 + hh * 64];
#pragma unroll
        for (int i = 0; i < 8; ++i) dst[i] = srcp[i];
    } else {
#pragma unroll
        for (int mi = 0; mi < 4; ++mi)
#pragma unroll
            for (int ni = 0; ni < 4; ++ni) {
                f16x4 pk = {(f16)(acc[mi][ni][0] + bvv[ni]), (f16)(acc[mi][ni][1] + bvv[ni]),
                            (f16)(acc[mi][ni][2] + bvv[ni]), (f16)(acc[mi][ni][3] + bvv[ni])};
                *(f16x4*)&Ct[(wc * 64 + ni * 16 + lg16) * 136 + wr * 64 + mi * 16 + lg4 * 4] = pk;
            }
        __syncthreads();
        const int r = tid >> 1, hh = tid & 1;
        float4* dst = (float4*)&Vt[((size_t)b * 512 + nb + r) * L + l0 + hh * 64];
        const float4* srcp = (const float4*)&Ct[r * 136 + hh * 64];
#pragma unroll
        for (int i = 0; i < 8; ++i) dst[i] = srcp[i];
    }
}

// ---------------------------------------------------------------------------
// Attention, two-pass: pass 1 computes softmax stats (m,l) + packs mask bits
// into registers (no A traffic); pass 2 recomputes S (bit-identical MFMA),
// writes final A once, and feeds thresholded normalized P into PV (no
// rescale, no final O normalize).  Saves 268 MB of A-region traffic + the
// serial sweep-2 phase vs the round-11 kernel.
// ---------------------------------------------------------------------------
__global__ __launch_bounds__(256) void attn_kernel(
    const f16* __restrict__ Qh, const f16* __restrict__ Kh, const f16* __restrict__ Vt,
    const float* __restrict__ w_pos, const int* __restrict__ amask,
    const float* __restrict__ vmaskp,
    float* __restrict__ Aout, f16* __restrict__ Oh)
{
    const int bh = blockIdx.y;
    const int b = bh >> 3, h = bh & 7;
    const int q0 = blockIdx.x * 64;
    const int tid = threadIdx.x;
    const int wv   = tid >> 6;
    const int lane = tid & 63;
    const int lg16 = lane & 15;
    const int lg4  = lane >> 4;

    __shared__ __align__(16) f16  smem_h[4608 * 4];   // Qs,Ks,Vs,es (rows*72)
    __shared__ __align__(16) float Ps[64 * 66];       // pos table P[qloc][rel 0..64]
    f16* const Qs = smem_h;
    f16* const Ks = smem_h + 4608;
    f16* const Vs = smem_h + 2 * 4608;
    f16* const es = smem_h + 3 * 4608;
    f16* const wps = Ks;            // phase-A alias

    // stage Q tile and w_pos
    for (int i = tid; i < 512; i += 256) {
        const int row = i >> 3, ch = i & 7;
        *(float4*)&Qs[row * 72 + ch * 8] =
            *(const float4*)&Qh[((size_t)bh * L + q0 + row) * 64 + ch * 8];
    }
    for (int i = tid; i < 640; i += 256) {
        const int r = i >> 3, ch = i & 7;
        f16 t[8];
        if (r < 65) {
            const float* s = w_pos + (size_t)r * 64 + ch * 8;
#pragma unroll
            for (int j = 0; j < 8; ++j) t[j] = (f16)s[j];
        } else {
#pragma unroll
            for (int j = 0; j < 8; ++j) t[j] = (f16)0.f;
        }
        *(float4*)&wps[r * 72 + ch * 8] = *(const float4*)t;
    }
    __syncthreads();

    f16x8 qa[2];
#pragma unroll
    for (int kc = 0; kc < 2; ++kc)
        qa[kc] = *(const f16x8*)&Qs[(wv * 16 + lg16) * 72 + kc * 32 + lg4 * 8];

    // P[qloc][r] = Q . w_pos[r] via MFMA
#pragma unroll
    for (int c = 0; c < 5; ++c) {
        f32x4 acc = {0.f, 0.f, 0.f, 0.f};
#pragma unroll
        for (int kc = 0; kc < 2; ++kc) {
            f16x8 wb = *(const f16x8*)&wps[(c * 16 + lg16) * 72 + kc * 32 + lg4 * 8];
            acc = __builtin_amdgcn_mfma_f32_16x16x32_f16(qa[kc], wb, acc, 0, 0, 0);
        }
        const int r = c * 16 + lg16;
        if (r < 65) {
#pragma unroll
            for (int j = 0; j < 4; ++j)
                Ps[(wv * 16 + lg4 * 4 + j) * 66 + r] = acc[j];
        }
    }

    const int qloc0 = wv * 16 + lg4 * 4;
    const size_t Abase = ((size_t)bh * L + q0 + qloc0) * L;

    float mrow[4], lrow[4];
#pragma unroll
    for (int j = 0; j < 4; ++j) { mrow[j] = -INFINITY; lrow[j] = 0.f; }
    unsigned int mbits[8] = {0, 0, 0, 0, 0, 0, 0, 0};

    // =================== pass 1: softmax stats (K only) ===================
    float4 kreg[2];
#pragma unroll
    for (int p = 0; p < 2; ++p) {
        const int it = tid + p * 256, row = it >> 3, ch = it & 7;
        kreg[p] = *(const float4*)&Kh[((size_t)bh * L + row) * 64 + ch * 8];
    }

    for (int kt = 0; kt < 16; ++kt) {
        const int kbase = kt * 64;
        __syncthreads();
#pragma unroll
        for (int p = 0; p < 2; ++p) {
            const int it = tid + p * 256, row = it >> 3, ch = it & 7;
            *(float4*)&Ks[row * 72 + ch * 8] = kreg[p];
        }
        __syncthreads();
        if (kt < 15) {
            const int kb2 = kbase + 64;
#pragma unroll
            for (int p = 0; p < 2; ++p) {
                const int it = tid + p * 256, row = it >> 3, ch = it & 7;
                kreg[p] = *(const float4*)&Kh[((size_t)bh * L + kb2 + row) * 64 + ch * 8];
            }
        }

        f32x4 sc[4];
#pragma unroll
        for (int c = 0; c < 4; ++c) {
            sc[c] = (f32x4){0.f, 0.f, 0.f, 0.f};
#pragma unroll
            for (int kc = 0; kc < 2; ++kc) {
                f16x8 kb = *(const f16x8*)&Ks[(c * 16 + lg16) * 72 + kc * 32 + lg4 * 8];
                sc[c] = __builtin_amdgcn_mfma_f32_16x16x32_f16(qa[kc], kb, sc[c], 0, 0, 0);
            }
        }

        float sv[4][4];
#pragma unroll
        for (int c = 0; c < 4; ++c) {
            const int kg = kbase + c * 16 + lg16;
#pragma unroll
            for (int j = 0; j < 4; ++j) {
                const int ql = qloc0 + j;
                const int qg = q0 + ql;
                int off = kg - qg;
                off = off < -32 ? -32 : (off > 32 ? 32 : off);
                float v = sc[c][j] * 0.125f + Ps[ql * 66 + off + 32];
                if (amask[(size_t)qg * L + kg] != 0) {
                    v = -INFINITY;
                    mbits[kt >> 1] |= 1u << ((kt & 1) * 16 + c * 4 + j);
                }
                sv[c][j] = v;
            }
        }

        float mn[4];
#pragma unroll
        for (int j = 0; j < 4; ++j) {
            float t = fmaxf(fmaxf(sv[0][j], sv[1][j]), fmaxf(sv[2][j], sv[3][j]));
            t = fmaxf(t, __shfl_xor(t, 1, 64));
            t = fmaxf(t, __shfl_xor(t, 2, 64));
            t = fmaxf(t, __shfl_xor(t, 4, 64));
            t = fmaxf(t, __shfl_xor(t, 8, 64));
            mn[j] = fmaxf(mrow[j], t);
        }
#pragma unroll
        for (int j = 0; j < 4; ++j) {
            float s = 0.f, al;
            if (mn[j] == -INFINITY) {
                al = 1.f;
            } else {
                al = __expf(mrow[j] - mn[j]);
#pragma unroll
                for (int c = 0; c < 4; ++c) s += __expf(sv[c][j] - mn[j]);
            }
            s += __shfl_xor(s, 1, 64);
            s += __shfl_xor(s, 2, 64);
            s += __shfl_xor(s, 4, 64);
            s += __shfl_xor(s, 8, 64);
            lrow[j] = lrow[j] * al + s;
            mrow[j] = mn[j];
        }
    }

    float il[4];
#pragma unroll
    for (int j = 0; j < 4; ++j) il[j] = lrow[j] > 0.f ? 1.f / lrow[j] : 0.f;
    const float vm = vmaskp[0];

    // =================== pass 2: A write + PV (K and V) ===================
    f32x4 Oc[4];
#pragma unroll
    for (int c = 0; c < 4; ++c) Oc[c] = (f32x4){0.f, 0.f, 0.f, 0.f};

    float4 vreg[2];
#pragma unroll
    for (int p = 0; p < 2; ++p) {
        const int it = tid + p * 256, row = it >> 3, ch = it & 7;
        kreg[p] = *(const float4*)&Kh[((size_t)bh * L + row) * 64 + ch * 8];
        vreg[p] = *(const float4*)&Vt[((size_t)(bh * 64 + row)) * L + ch * 8];
    }

    for (int kt = 0; kt < 16; ++kt) {
        const int kbase = kt * 64;
        __syncthreads();
#pragma unroll
        for (int p = 0; p < 2; ++p) {
            const int it = tid + p * 256, row = it >> 3, ch = it & 7;
            *(float4*)&Ks[row * 72 + ch * 8] = kreg[p];
            *(float4*)&Vs[row * 72 + ch * 8] = vreg[p];
        }
        __syncthreads();
        if (kt < 15) {
            const int kb2 = kbase + 64;
#pragma unroll
            for (int p = 0; p < 2; ++p) {
                const int it = tid + p * 256, row = it >> 3, ch = it & 7;
                kreg[p] = *(const float4*)&Kh[((size_t)bh * L + kb2 + row) * 64 + ch * 8];
                vreg[p] = *(const float4*)&Vt[((size_t)(bh * 64 + row)) * L + kb2 + ch * 8];
            }
        }

        f32x4 sc[4];
#pragma unroll
        for (int c = 0; c < 4; ++c) {
            sc[c] = (f32x4){0.f, 0.f, 0.f, 0.f};
#pragma unroll
            for (int kc = 0; kc < 2; ++kc) {
                f16x8 kb = *(const f16x8*)&Ks[(c * 16 + lg16) * 72 + kc * 32 + lg4 * 8];
                sc[c] = __builtin_amdgcn_mfma_f32_16x16x32_f16(qa[kc], kb, sc[c], 0, 0, 0);
            }
        }

        const unsigned int mw = mbits[kt >> 1] >> ((kt & 1) * 16);
#pragma unroll
        for (int c = 0; c < 4; ++c) {
            const int kg = kbase + c * 16 + lg16;
#pragma unroll
            for (int j = 0; j < 4; ++j) {
                const int ql = qloc0 + j;
                const int qg = q0 + ql;
                float a;
                if (((mw >> (c * 4 + j)) & 1u) || mrow[j] == -INFINITY) {
                    a = 0.f;
                } else {
                    int off = kg - qg;
                    off = off < -32 ? -32 : (off > 32 ? 32 : off);
                    const float s = sc[c][j] * 0.125f + Ps[ql * 66 + off + 32];
                    a = __expf(s - mrow[j]) * il[j];
                }
                if (!(a > vm)) a = 0.f;
                Aout[Abase + (size_t)j * L + kg] = a;
                es[(ql) * 72 + c * 16 + lg16] = (f16)a;
            }
        }
        asm volatile("s_waitcnt lgkmcnt(0)" ::: "memory");
        __builtin_amdgcn_sched_barrier(0);      // rule #18

        f16x8 ea[2];
#pragma unroll
        for (int kc = 0; kc < 2; ++kc)
            ea[kc] = *(const f16x8*)&es[(wv * 16 + lg16) * 72 + kc * 32 + lg4 * 8];
#pragma unroll
        for (int c = 0; c < 4; ++c)
#pragma unroll
            for (int kc = 0; kc < 2; ++kc) {
                f16x8 vb = *(const f16x8*)&Vs[(c * 16 + lg16) * 72 + kc * 32 + lg4 * 8];
                Oc[c] = __builtin_amdgcn_mfma_f32_16x16x32_f16(ea[kc], vb, Oc[c], 0, 0, 0);
            }
    }

    // O already normalized (P was normalized before PV)
#pragma unroll
    for (int c = 0; c < 4; ++c)
#pragma unroll
        for (int j = 0; j < 4; ++j)
            Oh[((size_t)b * L + q0 + qloc0 + j) * DOUT + h * 64 + c * 16 + lg16] =
                (f16)Oc[c][j];
}

// ---------------------------------------------------------------------------
// FC as f16 MFMA GEMM (unchanged).
// ---------------------------------------------------------------------------
__global__ __launch_bounds__(256) void fcg_kernel(
    const f16* __restrict__ Ohp, const float* __restrict__ Wfc,
    const float* __restrict__ bfc, float* __restrict__ outp)
{
    const int Mb = blockIdx.x * 128;
    const int Nb = blockIdx.y * 128;
    const int tid  = threadIdx.x;
    const int wvid = tid >> 6;
    const int lane = tid & 63;
    const int lg16 = lane & 15;
    const int lg4  = lane >> 4;
    const int wr = wvid >> 1, wc = wvid & 1;

    __shared__ __align__(16) f16 As[128 * 72];
    __shared__ __align__(16) f16 Bs[128 * 72];

    f32x4 acc[4][4];
#pragma unroll
    for (int mi = 0; mi < 4; ++mi)
#pragma unroll
        for (int ni = 0; ni < 4; ++ni) acc[mi][ni] = (f32x4){0.f, 0.f, 0.f, 0.f};

    const int r_st = tid >> 1;
    const int c_st = (tid & 1) * 32;

    for (int kc = 0; kc < 8; ++kc) {
        __syncthreads();
        {
            const f16* s = Ohp + (size_t)(Mb + r_st) * DOUT + kc * 64 + c_st;
#pragma unroll
            for (int g = 0; g < 4; ++g)
                *(float4*)&As[r_st * 72 + c_st + g * 8] = ((const float4*)s)[g];
        }
        {
            const float* s = Wfc + (size_t)(Nb + r_st) * DOUT + kc * 64 + c_st;
#pragma unroll
            for (int g = 0; g < 4; ++g) {
                float4 v0 = ((const float4*)s)[g * 2];
                float4 v1 = ((const float4*)s)[g * 2 + 1];
                f16 t[8] = {(f16)v0.x, (f16)v0.y, (f16)v0.z, (f16)v0.w,
                            (f16)v1.x, (f16)v1.y, (f16)v1.z, (f16)v1.w};
                *(float4*)&Bs[r_st * 72 + c_st + g * 8] = *(const float4*)t;
            }
        }
        __syncthreads();

#pragma unroll
        for (int ks = 0; ks < 2; ++ks) {
            f16x8 bb[4];
#pragma unroll
            for (int ni = 0; ni < 4; ++ni)
                bb[ni] = *(const f16x8*)&Bs[(wc * 64 + ni * 16 + lg16) * 72 + ks * 32 + lg4 * 8];
#pragma unroll
            for (int mi = 0; mi < 4; ++mi) {
                const f16x8 aa = *(const f16x8*)&As[(wr * 64 + mi * 16 + lg16) * 72 + ks * 32 + lg4 * 8];
#pragma unroll
                for (int ni = 0; ni < 4; ++ni)
                    acc[mi][ni] = __builtin_amdgcn_mfma_f32_16x16x32_f16(aa, bb[ni], acc[mi][ni], 0, 0, 0);
            }
        }
    }

#pragma unroll
    for (int ni = 0; ni < 4; ++ni) {
        const int col = Nb + wc * 64 + ni * 16 + lg16;
        const float bv = bfc[col];
#pragma unroll
        for (int mi = 0; mi < 4; ++mi) {
            const int row0 = Mb + wr * 64 + mi * 16 + lg4 * 4;
#pragma unroll
            for (int jr = 0; jr < 4; ++jr)
                outp[(size_t)(row0 + jr) * DOUT + col] = acc[mi][ni][jr] + bv;
        }
    }
}

// ---------------------------------------------------------------------------
extern "C" void kernel_launch(void* const* d_in, const int* in_sizes, int n_in,
                              void* d_out, int out_size, void* d_ws, size_t ws_size,
                              hipStream_t stream) {
    const float* q    = (const float*)d_in[0];
    const float* k    = (const float*)d_in[1];
    const float* v    = (const float*)d_in[2];
    const float* Wq   = (const float*)d_in[3];
    const float* bq   = (const float*)d_in[4];
    const float* Wk   = (const float*)d_in[5];
    const float* bk   = (const float*)d_in[6];
    const float* Wv   = (const float*)d_in[7];
    const float* bv   = (const float*)d_in[8];
    const float* Wfc  = (const float*)d_in[9];
    const float* bfc  = (const float*)d_in[10];
    const float* wpos = (const float*)d_in[11];
    const int*   amsk = (const int*)d_in[12];
    const float* vmsk = (const float*)d_in[13];

    f16* Qh  = (f16*)d_ws;                        // [bh][l][64]
    f16* Kh  = Qh  + (size_t)2097152;
    f16* Vt  = Kh  + (size_t)2097152;             // [b*512+co][l]
    f16* Ohh = Vt  + (size_t)2097152;             // [b][l][512]
    f16* Wp  = Ohh + (size_t)2097152;             // [3][512][768]

    float* outp = (float*)d_out;                  // [B][L][512]
    float* Aout = outp + (size_t)B * L * DOUT;    // [B][H][L][L]

    pack_kernel<<<dim3(512, 3), 256, 0, stream>>>(Wq, Wk, Wv, Wp);
    convg_kernel<<<dim3(32, 4, 3), 256, 0, stream>>>(
        q, k, v, Wp, bq, bk, bv, Qh, Kh, Vt);
    attn_kernel<<<dim3(L / 64, B * H), 256, 0, stream>>>(
        Qh, Kh, Vt, wpos, amsk, vmsk, Aout, Ohh);
    fcg_kernel<<<dim3(32, 4), 256, 0, stream>>>(
        Ohh, Wfc, bfc, outp);
}